// Round 3
// baseline (309.889 us; speedup 1.0000x reference)
//
#include <hip/hip_runtime.h>

// Problem constants
#define SEQ   2048
#define BATCH 16
#define CINCH 512
#define HDIM  512
#define NDIM  1536            // 3*H
#define TBM   (SEQ*BATCH)     // 32768 = GEMM M
#define KRED  1024            // Cin*K = GEMM K
#define NCH   128             // scan chunks
#define CHL   16              // chunk length (NCH*CHL == SEQ)
#define NCOL  8192            // B*H chains

typedef unsigned short ushort_t;
typedef __bf16 bf16x8 __attribute__((ext_vector_type(8)));
typedef unsigned short u16x8 __attribute__((ext_vector_type(8)));
typedef float f32x4 __attribute__((ext_vector_type(4)));

__device__ __forceinline__ float bf2f(ushort_t u) {
    return __uint_as_float(((unsigned int)u) << 16);
}
__device__ __forceinline__ ushort_t f2bf(float x) {
    unsigned int u = __float_as_uint(x);
    unsigned int r = u + 0x7fffu + ((u >> 16) & 1u);   // round-to-nearest-even
    return (ushort_t)(r >> 16);
}

// ---------------------------------------------------------------------------
// Kernel 1 (fused): cast x fp32 -> bf16 with BATCH*CINCH zero prefix (16B
// stores), and repack W (3H,Cin,2) -> Wb (3H,1024) bf16, Wb[o][k*512+ci].
// Blocks [0, CAST_BLK) do the cast; the rest do the repack.
// ---------------------------------------------------------------------------
#define CAST_BLK 8196   // (TBM+BATCH)*CINCH/8/256
#define RPK_BLK  6144   // NDIM*KRED/256
__global__ void prep_kernel(const float* __restrict__ x, ushort_t* __restrict__ xb,
                            const float* __restrict__ W, ushort_t* __restrict__ wb) {
    if (blockIdx.x < CAST_BLK) {
        int e = (blockIdx.x * 256 + threadIdx.x) * 8;
        u16x8 r;
        if (e < BATCH * CINCH) {
            r = (u16x8){0, 0, 0, 0, 0, 0, 0, 0};
        } else {
            const float* p = x + (e - BATCH * CINCH);
            float4 v0 = *(const float4*)p;
            float4 v1 = *(const float4*)(p + 4);
            r[0] = f2bf(v0.x); r[1] = f2bf(v0.y); r[2] = f2bf(v0.z); r[3] = f2bf(v0.w);
            r[4] = f2bf(v1.x); r[5] = f2bf(v1.y); r[6] = f2bf(v1.z); r[7] = f2bf(v1.w);
        }
        *(u16x8*)(xb + e) = r;
    } else {
        int i = (blockIdx.x - CAST_BLK) * 256 + threadIdx.x;   // 0 .. 1536*1024
        int o  = i >> 10;
        int r  = i & 1023;
        int k  = r >> 9;
        int ci = r & 511;
        wb[i] = f2bf(W[o * 1024 + ci * 2 + k]);
    }
}

// ---------------------------------------------------------------------------
// Kernel 2: GEMM + bias + activation -> bf16 gates z/f/o, each [T*B][H].
// 128x128 tile, BK=64, 4 waves, 16x16x32 bf16 MFMA, XOR-swizzled LDS,
// global_load_lds width=16 staging, LDS-transpose epilogue.
// Grid: x = N-block (12, fast axis) so the 12 blocks sharing an A-stripe are
// concurrent: A-stripe (256KB) + whole B (3MB) fit per-XCD L2.
// ---------------------------------------------------------------------------
__device__ __forceinline__ void load_lds_16B(const ushort_t* g, ushort_t* l) {
    auto* gp = reinterpret_cast<const __attribute__((address_space(1))) unsigned int*>(
        reinterpret_cast<uintptr_t>(g));
    auto* lp = reinterpret_cast<__attribute__((address_space(3))) unsigned int*>(
        reinterpret_cast<uintptr_t>(l));
    __builtin_amdgcn_global_load_lds(gp, lp, 16, 0, 0);
}

__global__ __launch_bounds__(256) void gemm_gates_kernel(
    const ushort_t* __restrict__ xb, const ushort_t* __restrict__ wb,
    const float* __restrict__ bias,
    ushort_t* __restrict__ zb, ushort_t* __restrict__ fb, ushort_t* __restrict__ ob) {

    __shared__ ushort_t smem[2 * 128 * 64];   // As/Bs in K-loop; 128x128 out-tile in epilogue
    ushort_t* As = smem;
    ushort_t* Bs = smem + 128 * 64;

    const int tid  = threadIdx.x;
    const int w    = tid >> 6;
    const int lane = tid & 63;
    const int quad = lane >> 4;
    const int l15  = lane & 15;
    const int wm   = w & 1;
    const int wn   = w >> 1;
    const int nBase = blockIdx.x * 128;   // fast axis: N
    const int mBase = blockIdx.y * 128;

    const int srow = lane >> 3;
    const int scb  = lane & 7;

    f32x4 acc[4][4];
#pragma unroll
    for (int i = 0; i < 4; ++i)
#pragma unroll
        for (int j = 0; j < 4; ++j)
            acc[i][j] = (f32x4){0.f, 0.f, 0.f, 0.f};

    for (int kt = 0; kt < 16; ++kt) {
        __syncthreads();
        const long aOff = (kt < 8) ? (long)kt * 64 : (long)16 * 512 + (long)(kt - 8) * 64;
#pragma unroll
        for (int i = 0; i < 4; ++i) {
            const int row = w * 32 + i * 8 + srow;
            const int cbd = scb ^ (row & 7);
            const ushort_t* ga = xb + (long)(mBase + row) * 512 + aOff + cbd * 8;
            load_lds_16B(ga, &As[(w * 32 + i * 8) * 64]);
            const ushort_t* gb = wb + (long)(nBase + row) * 1024 + kt * 64 + cbd * 8;
            load_lds_16B(gb, &Bs[(w * 32 + i * 8) * 64]);
        }
        __syncthreads();

#pragma unroll
        for (int ks = 0; ks < 2; ++ks) {
            bf16x8 af[4], bfr[4];
            const int cbd = ks * 4 + quad;
#pragma unroll
            for (int mt = 0; mt < 4; ++mt) {
                int ml  = wm * 64 + mt * 16 + l15;
                int off = ml * 64 + ((cbd ^ (ml & 7)) * 8);
                af[mt] = __builtin_bit_cast(bf16x8, *(const u16x8*)(&As[off]));
            }
#pragma unroll
            for (int nt = 0; nt < 4; ++nt) {
                int nl  = wn * 64 + nt * 16 + l15;
                int off = nl * 64 + ((cbd ^ (nl & 7)) * 8);
                bfr[nt] = __builtin_bit_cast(bf16x8, *(const u16x8*)(&Bs[off]));
            }
#pragma unroll
            for (int mt = 0; mt < 4; ++mt)
#pragma unroll
                for (int nt = 0; nt < 4; ++nt)
                    acc[mt][nt] = __builtin_amdgcn_mfma_f32_16x16x32_bf16(
                        af[mt], bfr[nt], acc[mt][nt], 0, 0, 0);
        }
    }

    // ---- Epilogue: bias + activation into LDS (swizzled), then coalesced stores
    const int gate = nBase >> 9;            // block-uniform: 4 N-tiles per gate
    const int hb   = nBase & 511;

    __syncthreads();
#pragma unroll
    for (int nt = 0; nt < 4; ++nt) {
        const int n_local = wn * 64 + nt * 16 + l15;
        const float bv = bias[nBase + n_local];
#pragma unroll
        for (int mt = 0; mt < 4; ++mt) {
#pragma unroll
            for (int r = 0; r < 4; ++r) {
                const int m_local = wm * 64 + mt * 16 + quad * 4 + r;
                float g = acc[mt][nt][r] + bv;
                float a;
                if (gate == 0) {
                    float e = __expf(-2.f * fabsf(g));
                    float t = (1.f - e) / (1.f + e);
                    a = copysignf(t, g);
                } else {
                    a = 1.f / (1.f + __expf(-g));
                }
                const int phys = ((n_local >> 3) ^ (m_local & 7)) * 8 + (n_local & 7);
                smem[m_local * 128 + phys] = f2bf(a);
            }
        }
    }
    __syncthreads();

    ushort_t* outp = (gate == 0) ? zb : (gate == 1) ? fb : ob;
#pragma unroll
    for (int s = 0; s < 8; ++s) {
        const int m_local = w * 32 + s * 4 + quad;
        const int blk = l15 ^ (m_local & 7);
        u16x8 v = *(const u16x8*)(&smem[m_local * 128 + blk * 8]);
        *(u16x8*)(outp + (long)(mBase + m_local) * 512 + hb + l15 * 8) = v;
    }
}

// ---------------------------------------------------------------------------
// Scan, chunked-parallel (3 passes), 8 columns per thread (16B loads).
// c = f*c + (1-f)*z ; h = c*o.
// ---------------------------------------------------------------------------
__global__ __launch_bounds__(256) void scan_compose(
    const ushort_t* __restrict__ zb, const ushort_t* __restrict__ fb,
    float* __restrict__ Acomp, float* __restrict__ Bcomp) {
    const int ch   = blockIdx.x >> 2;                       // 4 blocks per chunk
    const int col0 = (((blockIdx.x & 3) * 256) + threadIdx.x) * 8;
    const long base = (long)ch * CHL * NCOL + col0;

    float A[8], Bv[8];
#pragma unroll
    for (int j = 0; j < 8; ++j) { A[j] = 1.f; Bv[j] = 0.f; }

    u16x8 zc = *(const u16x8*)(zb + base);
    u16x8 fc = *(const u16x8*)(fb + base);
    for (int t = 0; t < CHL; ++t) {
        u16x8 zn, fn;
        if (t + 1 < CHL) {
            zn = *(const u16x8*)(zb + base + (long)(t + 1) * NCOL);
            fn = *(const u16x8*)(fb + base + (long)(t + 1) * NCOL);
        }
#pragma unroll
        for (int j = 0; j < 8; ++j) {
            float f = bf2f(fc[j]), z = bf2f(zc[j]);
            Bv[j] = f * Bv[j] + (1.f - f) * z;
            A[j] *= f;
        }
        zc = zn; fc = fn;
    }
#pragma unroll
    for (int j = 0; j < 4; ++j) {
        // two f32x4 stores
    }
    f32x4 a0 = {A[0], A[1], A[2], A[3]}, a1 = {A[4], A[5], A[6], A[7]};
    f32x4 b0 = {Bv[0], Bv[1], Bv[2], Bv[3]}, b1 = {Bv[4], Bv[5], Bv[6], Bv[7]};
    *(f32x4*)(Acomp + (long)ch * NCOL + col0)     = a0;
    *(f32x4*)(Acomp + (long)ch * NCOL + col0 + 4) = a1;
    *(f32x4*)(Bcomp + (long)ch * NCOL + col0)     = b0;
    *(f32x4*)(Bcomp + (long)ch * NCOL + col0 + 4) = b1;
}

__global__ void scan_prefix(const float* __restrict__ Acomp,
                            const float* __restrict__ Bcomp,
                            float* __restrict__ Cin) {
    const int col = blockIdx.x * 256 + threadIdx.x;
    float c = 0.f;
#pragma unroll 4
    for (int ch = 0; ch < NCH; ++ch) {
        Cin[ch * NCOL + col] = c;
        c = Acomp[ch * NCOL + col] * c + Bcomp[ch * NCOL + col];
    }
}

__global__ __launch_bounds__(256) void scan_apply(
    const ushort_t* __restrict__ zb, const ushort_t* __restrict__ fb,
    const ushort_t* __restrict__ ob, const float* __restrict__ Cin,
    float* __restrict__ out) {
    const int ch   = blockIdx.x >> 2;
    const int col0 = (((blockIdx.x & 3) * 256) + threadIdx.x) * 8;
    const long base = (long)ch * CHL * NCOL + col0;

    float c[8], h[8];
    f32x4 c0 = *(const f32x4*)(Cin + (long)ch * NCOL + col0);
    f32x4 c1 = *(const f32x4*)(Cin + (long)ch * NCOL + col0 + 4);
    c[0] = c0[0]; c[1] = c0[1]; c[2] = c0[2]; c[3] = c0[3];
    c[4] = c1[0]; c[5] = c1[1]; c[6] = c1[2]; c[7] = c1[3];

    u16x8 zc = *(const u16x8*)(zb + base);
    u16x8 fc = *(const u16x8*)(fb + base);
    u16x8 oc = *(const u16x8*)(ob + base);
    for (int t = 0; t < CHL; ++t) {
        u16x8 zn, fn, on;
        if (t + 1 < CHL) {
            zn = *(const u16x8*)(zb + base + (long)(t + 1) * NCOL);
            fn = *(const u16x8*)(fb + base + (long)(t + 1) * NCOL);
            on = *(const u16x8*)(ob + base + (long)(t + 1) * NCOL);
        }
#pragma unroll
        for (int j = 0; j < 8; ++j) {
            float f = bf2f(fc[j]), z = bf2f(zc[j]), o = bf2f(oc[j]);
            c[j] = f * c[j] + (1.f - f) * z;
            h[j] = c[j] * o;
        }
        f32x4 h0 = {h[0], h[1], h[2], h[3]}, h1 = {h[4], h[5], h[6], h[7]};
        *(f32x4*)(out + base + (long)t * NCOL)     = h0;
        *(f32x4*)(out + base + (long)t * NCOL + 4) = h1;
        zc = zn; fc = fn; oc = on;
    }
    if (ch == NCH - 1) {
        f32x4 h0 = {h[0], h[1], h[2], h[3]}, h1 = {h[4], h[5], h[6], h[7]};
        f32x4 cc0 = {c[0], c[1], c[2], c[3]}, cc1 = {c[4], c[5], c[6], c[7]};
        *(f32x4*)(out + (long)SEQ * NCOL + col0)            = h0;
        *(f32x4*)(out + (long)SEQ * NCOL + col0 + 4)        = h1;
        *(f32x4*)(out + (long)SEQ * NCOL + NCOL + col0)     = cc0;
        *(f32x4*)(out + (long)SEQ * NCOL + NCOL + col0 + 4) = cc1;
    }
}

// ---------------------------------------------------------------------------
extern "C" void kernel_launch(void* const* d_in, const int* in_sizes, int n_in,
                              void* d_out, int out_size, void* d_ws, size_t ws_size,
                              hipStream_t stream) {
    const float* x  = (const float*)d_in[0];   // (T, B, Cin)
    const float* W  = (const float*)d_in[1];   // (3H, Cin, 2)
    const float* bi = (const float*)d_in[2];   // (3H,)
    float* out = (float*)d_out;

    char* ws = (char*)d_ws;
    const size_t xbN = (size_t)(TBM + BATCH) * CINCH;   // padded bf16 x
    const size_t wbN = (size_t)NDIM * KRED;
    const size_t gN  = (size_t)TBM * HDIM;
    ushort_t* xb = (ushort_t*)ws;
    ushort_t* wb = (ushort_t*)(ws + xbN * 2);
    ushort_t* zb = (ushort_t*)(ws + xbN * 2 + wbN * 2);
    ushort_t* fb = zb + gN;
    ushort_t* ob = fb + gN;
    // scan scratch reuses the xb region (dead after the GEMM): 12 MB << 33.5 MB
    float* Acomp = (float*)ws;
    float* Bcomp = Acomp + NCH * NCOL;
    float* Cin   = Bcomp + NCH * NCOL;

    prep_kernel<<<CAST_BLK + RPK_BLK, 256, 0, stream>>>(x, xb, W, wb);
    dim3 ggrid(NDIM / 128, TBM / 128);   // N fast axis
    gemm_gates_kernel<<<ggrid, 256, 0, stream>>>(xb, wb, bi, zb, fb, ob);
    scan_compose<<<NCH * 4, 256, 0, stream>>>(zb, fb, Acomp, Bcomp);
    scan_prefix<<<NCOL / 256, 256, 0, stream>>>(Acomp, Bcomp, Cin);
    scan_apply<<<NCH * 4, 256, 0, stream>>>(zb, fb, ob, Cin, out);
}

// Round 4
// 308.174 us; speedup vs baseline: 1.0056x; 1.0056x over previous
//
#include <hip/hip_runtime.h>

// Problem constants
#define SEQ   2048
#define BATCH 16
#define CINCH 512
#define HDIM  512
#define NDIM  1536            // 3*H
#define TBM   (SEQ*BATCH)     // 32768 = GEMM M
#define KRED  1024            // Cin*K = GEMM K
#define NCH   256             // scan chunks
#define CHL   8               // chunk length (NCH*CHL == SEQ)
#define NCOL  8192            // B*H chains

typedef unsigned short ushort_t;
typedef __bf16 bf16x8 __attribute__((ext_vector_type(8)));
typedef unsigned short u16x8 __attribute__((ext_vector_type(8)));
typedef float f32x4 __attribute__((ext_vector_type(4)));

__device__ __forceinline__ float bf2f(ushort_t u) {
    return __uint_as_float(((unsigned int)u) << 16);
}
__device__ __forceinline__ ushort_t f2bf(float x) {
    unsigned int u = __float_as_uint(x);
    unsigned int r = u + 0x7fffu + ((u >> 16) & 1u);   // round-to-nearest-even
    return (ushort_t)(r >> 16);
}

// ---------------------------------------------------------------------------
// Kernel 1 (fused): cast x fp32 -> bf16 with BATCH*CINCH zero prefix (16B
// stores), and repack W (3H,Cin,2) -> Wb (3H,1024) bf16, Wb[o][k*512+ci].
// ---------------------------------------------------------------------------
#define CAST_BLK 8196   // (TBM+BATCH)*CINCH/8/256
#define RPK_BLK  6144   // NDIM*KRED/256
__global__ void prep_kernel(const float* __restrict__ x, ushort_t* __restrict__ xb,
                            const float* __restrict__ W, ushort_t* __restrict__ wb) {
    if (blockIdx.x < CAST_BLK) {
        int e = (blockIdx.x * 256 + threadIdx.x) * 8;
        u16x8 r;
        if (e < BATCH * CINCH) {
            r = (u16x8){0, 0, 0, 0, 0, 0, 0, 0};
        } else {
            const float* p = x + (e - BATCH * CINCH);
            float4 v0 = *(const float4*)p;
            float4 v1 = *(const float4*)(p + 4);
            r[0] = f2bf(v0.x); r[1] = f2bf(v0.y); r[2] = f2bf(v0.z); r[3] = f2bf(v0.w);
            r[4] = f2bf(v1.x); r[5] = f2bf(v1.y); r[6] = f2bf(v1.z); r[7] = f2bf(v1.w);
        }
        *(u16x8*)(xb + e) = r;
    } else {
        int i = (blockIdx.x - CAST_BLK) * 256 + threadIdx.x;   // 0 .. 1536*1024
        int o  = i >> 10;
        int r  = i & 1023;
        int k  = r >> 9;
        int ci = r & 511;
        wb[i] = f2bf(W[o * 1024 + ci * 2 + k]);
    }
}

// ---------------------------------------------------------------------------
// Kernel 2: GEMM + bias + activation -> bf16 gates z/f/o, each [T*B][H].
// 128x128 tile, BK=64, 4 waves, 16x16x32 bf16 MFMA, XOR-swizzled LDS,
// global_load_lds width=16 staging, LDS-transpose epilogue.
// Grid: M fast axis (R2 config — measured FETCH 139MB / 132.6us; N-fast
// regressed to 274MB from cross-XCD A-stripe duplication).
// ---------------------------------------------------------------------------
__device__ __forceinline__ void load_lds_16B(const ushort_t* g, ushort_t* l) {
    auto* gp = reinterpret_cast<const __attribute__((address_space(1))) unsigned int*>(
        reinterpret_cast<uintptr_t>(g));
    auto* lp = reinterpret_cast<__attribute__((address_space(3))) unsigned int*>(
        reinterpret_cast<uintptr_t>(l));
    __builtin_amdgcn_global_load_lds(gp, lp, 16, 0, 0);
}

__global__ __launch_bounds__(256) void gemm_gates_kernel(
    const ushort_t* __restrict__ xb, const ushort_t* __restrict__ wb,
    const float* __restrict__ bias,
    ushort_t* __restrict__ zb, ushort_t* __restrict__ fb, ushort_t* __restrict__ ob) {

    __shared__ ushort_t smem[2 * 128 * 64];   // As/Bs in K-loop; 128x128 out-tile in epilogue
    ushort_t* As = smem;
    ushort_t* Bs = smem + 128 * 64;

    const int tid  = threadIdx.x;
    const int w    = tid >> 6;
    const int lane = tid & 63;
    const int quad = lane >> 4;
    const int l15  = lane & 15;
    const int wm   = w & 1;
    const int wn   = w >> 1;
    const int mBase = blockIdx.x * 128;   // fast axis: M
    const int nBase = blockIdx.y * 128;

    const int srow = lane >> 3;
    const int scb  = lane & 7;

    f32x4 acc[4][4];
#pragma unroll
    for (int i = 0; i < 4; ++i)
#pragma unroll
        for (int j = 0; j < 4; ++j)
            acc[i][j] = (f32x4){0.f, 0.f, 0.f, 0.f};

    for (int kt = 0; kt < 16; ++kt) {
        __syncthreads();
        const long aOff = (kt < 8) ? (long)kt * 64 : (long)16 * 512 + (long)(kt - 8) * 64;
#pragma unroll
        for (int i = 0; i < 4; ++i) {
            const int row = w * 32 + i * 8 + srow;
            const int cbd = scb ^ (row & 7);
            const ushort_t* ga = xb + (long)(mBase + row) * 512 + aOff + cbd * 8;
            load_lds_16B(ga, &As[(w * 32 + i * 8) * 64]);
            const ushort_t* gb = wb + (long)(nBase + row) * 1024 + kt * 64 + cbd * 8;
            load_lds_16B(gb, &Bs[(w * 32 + i * 8) * 64]);
        }
        __syncthreads();

#pragma unroll
        for (int ks = 0; ks < 2; ++ks) {
            bf16x8 af[4], bfr[4];
            const int cbd = ks * 4 + quad;
#pragma unroll
            for (int mt = 0; mt < 4; ++mt) {
                int ml  = wm * 64 + mt * 16 + l15;
                int off = ml * 64 + ((cbd ^ (ml & 7)) * 8);
                af[mt] = __builtin_bit_cast(bf16x8, *(const u16x8*)(&As[off]));
            }
#pragma unroll
            for (int nt = 0; nt < 4; ++nt) {
                int nl  = wn * 64 + nt * 16 + l15;
                int off = nl * 64 + ((cbd ^ (nl & 7)) * 8);
                bfr[nt] = __builtin_bit_cast(bf16x8, *(const u16x8*)(&Bs[off]));
            }
#pragma unroll
            for (int mt = 0; mt < 4; ++mt)
#pragma unroll
                for (int nt = 0; nt < 4; ++nt)
                    acc[mt][nt] = __builtin_amdgcn_mfma_f32_16x16x32_bf16(
                        af[mt], bfr[nt], acc[mt][nt], 0, 0, 0);
        }
    }

    // ---- Epilogue: bias + activation into LDS (swizzled), then coalesced stores
    const int gate = nBase >> 9;            // block-uniform: 4 N-tiles per gate
    const int hb   = nBase & 511;

    __syncthreads();
#pragma unroll
    for (int nt = 0; nt < 4; ++nt) {
        const int n_local = wn * 64 + nt * 16 + l15;
        const float bv = bias[nBase + n_local];
#pragma unroll
        for (int mt = 0; mt < 4; ++mt) {
#pragma unroll
            for (int r = 0; r < 4; ++r) {
                const int m_local = wm * 64 + mt * 16 + quad * 4 + r;
                float g = acc[mt][nt][r] + bv;
                float a;
                if (gate == 0) {
                    float e = __expf(-2.f * fabsf(g));
                    float t = (1.f - e) / (1.f + e);
                    a = copysignf(t, g);
                } else {
                    a = 1.f / (1.f + __expf(-g));
                }
                const int phys = ((n_local >> 3) ^ (m_local & 7)) * 8 + (n_local & 7);
                smem[m_local * 128 + phys] = f2bf(a);
            }
        }
    }
    __syncthreads();

    ushort_t* outp = (gate == 0) ? zb : (gate == 1) ? fb : ob;
#pragma unroll
    for (int s = 0; s < 8; ++s) {
        const int m_local = w * 32 + s * 4 + quad;
        const int blk = l15 ^ (m_local & 7);
        u16x8 v = *(const u16x8*)(&smem[m_local * 128 + blk * 8]);
        *(u16x8*)(outp + (long)(mBase + m_local) * 512 + hb + l15 * 8) = v;
    }
}

// ---------------------------------------------------------------------------
// Scan, chunked-parallel (3 passes), 8 columns/thread, CHL=8 fully unrolled
// with ALL loads hoisted (deep MLP: 16-24 16B loads in flight per thread).
// c = f*c + (1-f)*z ; h = c*o.
// ---------------------------------------------------------------------------
__global__ __launch_bounds__(256) void scan_compose(
    const ushort_t* __restrict__ zb, const ushort_t* __restrict__ fb,
    float* __restrict__ Acomp, float* __restrict__ Bcomp) {
    const int ch   = blockIdx.x >> 2;                       // 4 blocks per chunk
    const int col0 = (((blockIdx.x & 3) * 256) + threadIdx.x) * 8;
    const long base = (long)ch * CHL * NCOL + col0;

    u16x8 zc[CHL], fc[CHL];
#pragma unroll
    for (int t = 0; t < CHL; ++t) {
        zc[t] = *(const u16x8*)(zb + base + (long)t * NCOL);
        fc[t] = *(const u16x8*)(fb + base + (long)t * NCOL);
    }
    float A[8], Bv[8];
#pragma unroll
    for (int j = 0; j < 8; ++j) { A[j] = 1.f; Bv[j] = 0.f; }
#pragma unroll
    for (int t = 0; t < CHL; ++t) {
#pragma unroll
        for (int j = 0; j < 8; ++j) {
            float f = bf2f(fc[t][j]), z = bf2f(zc[t][j]);
            Bv[j] = f * Bv[j] + (1.f - f) * z;
            A[j] *= f;
        }
    }
    f32x4 a0 = {A[0], A[1], A[2], A[3]}, a1 = {A[4], A[5], A[6], A[7]};
    f32x4 b0 = {Bv[0], Bv[1], Bv[2], Bv[3]}, b1 = {Bv[4], Bv[5], Bv[6], Bv[7]};
    *(f32x4*)(Acomp + (long)ch * NCOL + col0)     = a0;
    *(f32x4*)(Acomp + (long)ch * NCOL + col0 + 4) = a1;
    *(f32x4*)(Bcomp + (long)ch * NCOL + col0)     = b0;
    *(f32x4*)(Bcomp + (long)ch * NCOL + col0 + 4) = b1;
}

__global__ void scan_prefix(const float* __restrict__ Acomp,
                            const float* __restrict__ Bcomp,
                            float* __restrict__ Cin) {
    const int col = blockIdx.x * 256 + threadIdx.x;
    float c = 0.f;
#pragma unroll 8
    for (int ch = 0; ch < NCH; ++ch) {
        Cin[ch * NCOL + col] = c;
        c = Acomp[ch * NCOL + col] * c + Bcomp[ch * NCOL + col];
    }
}

__global__ __launch_bounds__(256) void scan_apply(
    const ushort_t* __restrict__ zb, const ushort_t* __restrict__ fb,
    const ushort_t* __restrict__ ob, const float* __restrict__ Cin,
    float* __restrict__ out) {
    const int ch   = blockIdx.x >> 2;
    const int col0 = (((blockIdx.x & 3) * 256) + threadIdx.x) * 8;
    const long base = (long)ch * CHL * NCOL + col0;

    u16x8 zc[CHL], fc[CHL], oc[CHL];
#pragma unroll
    for (int t = 0; t < CHL; ++t) {
        zc[t] = *(const u16x8*)(zb + base + (long)t * NCOL);
        fc[t] = *(const u16x8*)(fb + base + (long)t * NCOL);
        oc[t] = *(const u16x8*)(ob + base + (long)t * NCOL);
    }
    float c[8], h[8];
    f32x4 c0 = *(const f32x4*)(Cin + (long)ch * NCOL + col0);
    f32x4 c1 = *(const f32x4*)(Cin + (long)ch * NCOL + col0 + 4);
    c[0] = c0[0]; c[1] = c0[1]; c[2] = c0[2]; c[3] = c0[3];
    c[4] = c1[0]; c[5] = c1[1]; c[6] = c1[2]; c[7] = c1[3];

#pragma unroll
    for (int t = 0; t < CHL; ++t) {
#pragma unroll
        for (int j = 0; j < 8; ++j) {
            float f = bf2f(fc[t][j]), z = bf2f(zc[t][j]), o = bf2f(oc[t][j]);
            c[j] = f * c[j] + (1.f - f) * z;
            h[j] = c[j] * o;
        }
        f32x4 h0 = {h[0], h[1], h[2], h[3]}, h1 = {h[4], h[5], h[6], h[7]};
        *(f32x4*)(out + base + (long)t * NCOL)     = h0;
        *(f32x4*)(out + base + (long)t * NCOL + 4) = h1;
    }
    if (ch == NCH - 1) {
        f32x4 h0 = {h[0], h[1], h[2], h[3]}, h1 = {h[4], h[5], h[6], h[7]};
        f32x4 cc0 = {c[0], c[1], c[2], c[3]}, cc1 = {c[4], c[5], c[6], c[7]};
        *(f32x4*)(out + (long)SEQ * NCOL + col0)            = h0;
        *(f32x4*)(out + (long)SEQ * NCOL + col0 + 4)        = h1;
        *(f32x4*)(out + (long)SEQ * NCOL + NCOL + col0)     = cc0;
        *(f32x4*)(out + (long)SEQ * NCOL + NCOL + col0 + 4) = cc1;
    }
}

// ---------------------------------------------------------------------------
extern "C" void kernel_launch(void* const* d_in, const int* in_sizes, int n_in,
                              void* d_out, int out_size, void* d_ws, size_t ws_size,
                              hipStream_t stream) {
    const float* x  = (const float*)d_in[0];   // (T, B, Cin)
    const float* W  = (const float*)d_in[1];   // (3H, Cin, 2)
    const float* bi = (const float*)d_in[2];   // (3H,)
    float* out = (float*)d_out;

    char* ws = (char*)d_ws;
    const size_t xbN = (size_t)(TBM + BATCH) * CINCH;   // padded bf16 x
    const size_t wbN = (size_t)NDIM * KRED;
    const size_t gN  = (size_t)TBM * HDIM;
    ushort_t* xb = (ushort_t*)ws;
    ushort_t* wb = (ushort_t*)(ws + xbN * 2);
    ushort_t* zb = (ushort_t*)(ws + xbN * 2 + wbN * 2);
    ushort_t* fb = zb + gN;
    ushort_t* ob = fb + gN;
    // scan scratch reuses the xb region (dead after the GEMM): 24 MB < 33.5 MB
    float* Acomp = (float*)ws;
    float* Bcomp = Acomp + NCH * NCOL;
    float* Cin   = Bcomp + NCH * NCOL;

    prep_kernel<<<CAST_BLK + RPK_BLK, 256, 0, stream>>>(x, xb, W, wb);
    dim3 ggrid(TBM / 128, NDIM / 128);   // M fast axis
    gemm_gates_kernel<<<ggrid, 256, 0, stream>>>(xb, wb, bi, zb, fb, ob);
    scan_compose<<<NCH * 4, 256, 0, stream>>>(zb, fb, Acomp, Bcomp);
    scan_prefix<<<NCOL / 256, 256, 0, stream>>>(Acomp, Bcomp, Cin);
    scan_apply<<<NCH * 4, 256, 0, stream>>>(zb, fb, ob, Cin, out);
}